// Round 1
// baseline (129.244 us; speedup 1.0000x reference)
//
#include <hip/hip_runtime.h>

typedef __attribute__((ext_vector_type(8))) short bf16x8;
typedef __attribute__((ext_vector_type(4))) float f32x4;
typedef __attribute__((ext_vector_type(4))) unsigned int u32x4;

static __device__ __forceinline__ unsigned short f2bf(float v) {
    unsigned int u = __builtin_bit_cast(unsigned int, v);
    u += 0x7fffu + ((u >> 16) & 1u);   // RNE; inputs are finite
    return (unsigned short)(u >> 16);
}

// ---------------------------------------------------------------------------
// Prep: fold all Hadamard transforms into direct-conv weights.
// Weff_t[n'][k] bf16, n' = o*4 + P*2 + Q (512 rows), k = c*16 + b*4 + a (1024)
// ---------------------------------------------------------------------------
__global__ void prep_weff(const float* __restrict__ w, unsigned short* __restrict__ weff)
{
    int idx = blockIdx.x * blockDim.x + threadIdx.x;
    if (idx >= 128 * 64) return;
    int o = idx >> 6, c = idx & 63;
    const bool v2 = (o >= 64);
    const float Hm[4][4]  = {{1,1,1,1},{1,-1,1,-1},{1,1,-1,-1},{1,-1,-1,1}};
    const float H2m[4][4] = {{1,-1,1,-1},{1,1,1,1},{1,1,-1,-1},{1,-1,-1,1}};

    float wv[4][4];
    #pragma unroll
    for (int i = 0; i < 4; ++i)
        #pragma unroll
        for (int j = 0; j < 4; ++j)
            wv[i][j] = w[((o * 64 + c) * 4 + i) * 4 + j];

    // FA[a][i]: v1 -> H[i][a] ('ia'), v2 -> H2[a][i] ('ai')
    // FB[b][j]: v1 -> H[b][j],        v2 -> H2[b][j]
    // G[p][i] = 0.25 * Hv[p+1][i]  (IH rows)
    float FA[4][4], FB[4][4], G[2][4];
    #pragma unroll
    for (int a = 0; a < 4; ++a)
        #pragma unroll
        for (int i = 0; i < 4; ++i) {
            FA[a][i] = v2 ? H2m[a][i] : Hm[i][a];
            FB[a][i] = v2 ? H2m[a][i] : Hm[a][i];
        }
    #pragma unroll
    for (int p = 0; p < 2; ++p)
        #pragma unroll
        for (int i = 0; i < 4; ++i)
            G[p][i] = 0.25f * (v2 ? H2m[p + 1][i] : Hm[p + 1][i]);

    #pragma unroll
    for (int P = 0; P < 2; ++P)
    #pragma unroll
    for (int Q = 0; Q < 2; ++Q) {
        int nrow = o * 4 + P * 2 + Q;
        #pragma unroll
        for (int b = 0; b < 4; ++b)
        #pragma unroll
        for (int a = 0; a < 4; ++a) {
            float s = 0.f;
            #pragma unroll
            for (int i = 0; i < 4; ++i) {
                float sj = 0.f;
                #pragma unroll
                for (int j = 0; j < 4; ++j)
                    sj += FB[b][j] * G[Q][j] * wv[i][j];
                s += G[P][i] * FA[a][i] * sj;
            }
            weff[(size_t)nrow * 1024 + c * 16 + b * 4 + a] = f2bf(s);
        }
    }
}

// ---------------------------------------------------------------------------
// Main GEMM: C[t][n'] = im2col(x)[t][k] * Weff_t[n'][k]
// M=25088 (196x128), N=512 (4x128), K=1024 (16x64). bf16 MFMA 16x16x32.
// ---------------------------------------------------------------------------
#define BM 128
#define BN 128
#define BK 64

__global__ __launch_bounds__(256) void winograd_conv(
    const float* __restrict__ x,
    const unsigned short* __restrict__ weff,
    const float* __restrict__ bias,
    float* __restrict__ out)
{
    __shared__ __align__(16) unsigned char smem[(BM + BN) * BK * 2]; // 16KB A + 16KB B
    __shared__ int s_xoff[BM];
    __shared__ int s_obase[BM];
    __shared__ unsigned int s_hw[BM];

    unsigned char* Abase = smem;
    unsigned char* Bbase = smem + BM * BK * 2;

    const int tid  = threadIdx.x;
    const int lane = tid & 63;
    const int wv   = tid >> 6;
    const int wm   = wv >> 1, wn = wv & 1;
    const int bid  = blockIdx.x;
    const int t0   = (bid >> 2) * BM;   // N-tile fastest -> A-panel L2 reuse
    const int n0g  = (bid & 3) * BN;

    if (tid < BM) {
        int t = t0 + tid;
        int nimg = t / 784;
        int rem  = t - nimg * 784;
        int h = rem / 28;
        int w = rem - h * 28;
        s_xoff[tid]  = nimg * (64 * 3136)  + (2 * h) * 56 + 2 * w;  // x[n,0,2h,2w]
        s_obase[tid] = nimg * (128 * 3136) + (2 * h) * 56 + 2 * w;  // out[n,0,2h,2w]
        s_hw[tid] = (unsigned)h | ((unsigned)w << 16);
    }
    __syncthreads();

    f32x4 acc[4][4];
    #pragma unroll
    for (int i = 0; i < 4; ++i)
        #pragma unroll
        for (int j = 0; j < 4; ++j)
            acc[i][j] = (f32x4){0.f, 0.f, 0.f, 0.f};

    for (int kstep = 0; kstep < 16; ++kstep) {
        const int c0 = kstep * 4;

        // ---- stage A: im2col gather, 512 (tile, c) pairs, 16 taps each ----
        #pragma unroll
        for (int it = 0; it < 2; ++it) {
            int pp = tid + it * 256;
            int tl = pp >> 2;
            int cc = pp & 3;
            unsigned int hw = s_hw[tl];
            int h = (int)(hw & 0xffffu), w = (int)(hw >> 16);
            const float* xc = x + s_xoff[tl] + (c0 + cc) * 3136;
            union { unsigned short us[16]; u32x4 q[2]; } buf;
            #pragma unroll
            for (int b = 0; b < 4; ++b) {
                int r = 2 * h + b - 1;
                bool rok = (r >= 0) && (r < 56);
                #pragma unroll
                for (int a = 0; a < 4; ++a) {
                    int cix = 2 * w + a - 1;
                    bool ok = rok && (cix >= 0) && (cix < 56);
                    float v = ok ? xc[(b - 1) * 56 + (a - 1)] : 0.f;
                    buf.us[b * 4 + a] = f2bf(v);
                }
            }
            int bb = tl * 128 + cc * 32;
            int sw = (tl & 7) << 4;                       // XOR swizzle (G4)
            *(u32x4*)(Abase + ( bb        ^ sw)) = buf.q[0];
            *(u32x4*)(Abase + ((bb + 16)  ^ sw)) = buf.q[1];
        }

        // ---- stage B: copy Weff rows (n'-major, k contiguous) ----
        {
            int nl = tid >> 1, hf = tid & 1;
            const u32x4* src = (const u32x4*)(weff + (size_t)(n0g + nl) * 1024 + kstep * 64 + hf * 32);
            int bb = nl * 128 + hf * 64;
            int sw = (nl & 7) << 4;
            #pragma unroll
            for (int j = 0; j < 4; ++j)
                *(u32x4*)(Bbase + ((bb + j * 16) ^ sw)) = src[j];
        }
        __syncthreads();

        // ---- MFMA: 2 k-substeps x 4x4 fragments per wave ----
        #pragma unroll
        for (int ks = 0; ks < 2; ++ks) {
            bf16x8 af[4], bg[4];
            #pragma unroll
            for (int fm = 0; fm < 4; ++fm) {
                int m = wm * 64 + fm * 16 + (lane & 15);
                int byteoff = (m * 128 + ks * 64 + (lane >> 4) * 16) ^ ((m & 7) << 4);
                af[fm] = *(const bf16x8*)(Abase + byteoff);
            }
            #pragma unroll
            for (int fn = 0; fn < 4; ++fn) {
                int n = wn * 64 + fn * 16 + (lane & 15);
                int byteoff = (n * 128 + ks * 64 + (lane >> 4) * 16) ^ ((n & 7) << 4);
                bg[fn] = *(const bf16x8*)(Bbase + byteoff);
            }
            #pragma unroll
            for (int fm = 0; fm < 4; ++fm)
                #pragma unroll
                for (int fn = 0; fn < 4; ++fn)
                    acc[fm][fn] = __builtin_amdgcn_mfma_f32_16x16x32_bf16(
                        af[fm], bg[fn], acc[fm][fn], 0, 0, 0);
        }
        __syncthreads();
    }

    // ---- epilogue: D col = lane&15 (n'), row = (lane>>4)*4+reg (m) ----
    #pragma unroll
    for (int fn = 0; fn < 4; ++fn) {
        int ng = n0g + wn * 64 + fn * 16 + (lane & 15);
        int o = ng >> 2;
        int P = (ng >> 1) & 1;
        int Q = ng & 1;
        float bo = bias[o];
        int ooff = o * 3136 + P * 56 + Q;
        #pragma unroll
        for (int fm = 0; fm < 4; ++fm) {
            int mb = wm * 64 + fm * 16 + ((lane >> 4) << 2);
            #pragma unroll
            for (int r = 0; r < 4; ++r)
                out[s_obase[mb + r] + ooff] = acc[fm][fn][r] + bo;
        }
    }
}

extern "C" void kernel_launch(void* const* d_in, const int* in_sizes, int n_in,
                              void* d_out, int out_size, void* d_ws, size_t ws_size,
                              hipStream_t stream)
{
    const float* x = (const float*)d_in[0];
    const float* w = (const float*)d_in[1];
    const float* b = (const float*)d_in[2];
    float* out = (float*)d_out;
    unsigned short* weff = (unsigned short*)d_ws;   // 512*1024*2 = 1 MB

    hipLaunchKernelGGL(prep_weff, dim3(32), dim3(256), 0, stream, w, weff);
    hipLaunchKernelGGL(winograd_conv, dim3(196 * 4), dim3(256), 0, stream, x, weff, b, out);
}

// Round 2
// 89.007 us; speedup vs baseline: 1.4521x; 1.4521x over previous
//
#include <hip/hip_runtime.h>

typedef __attribute__((ext_vector_type(8))) short bf16x8;
typedef __attribute__((ext_vector_type(4))) float f32x4;
typedef __attribute__((ext_vector_type(4))) unsigned int u32x4;

#define XP_ELEMS (2048 * 3364)      // padded x, bf16: 32*64 planes of 58x58
#define XP_BYTES (XP_ELEMS * 2)     // 13,778,944 bytes
#define BSTG_OFF XP_BYTES           // staged B: 4 groups * 16 ksteps * 16KB = 1MB

static __device__ __forceinline__ unsigned short f2bf(float v) {
    unsigned int u = __builtin_bit_cast(unsigned int, v);
    u += 0x7fffu + ((u >> 16) & 1u);
    return (unsigned short)(u >> 16);
}

// ---------------------------------------------------------------------------
// Prep: (a) pad+convert x to bf16 58x58 planes; (b) fold Hadamard transforms
// into direct-conv weights, stored in the swizzled LDS-tile layout.
// ---------------------------------------------------------------------------
__global__ __launch_bounds__(256) void prep(const float* __restrict__ x,
                                            const float* __restrict__ w,
                                            unsigned char* __restrict__ ws)
{
    int bid = blockIdx.x;
    if (bid < 2048) {
        // pad one (n,c) plane: 56x56 f32 -> 58x58 bf16 with zero border
        const float* src = x + (size_t)bid * 3136;
        unsigned short* dst = (unsigned short*)ws + (size_t)bid * 3364;
        for (int i = threadIdx.x; i < 3364; i += 256) {
            int r = i / 58, c = i - r * 58;
            float v = 0.f;
            if (r >= 1 && r <= 56 && c >= 1 && c <= 56)
                v = src[(r - 1) * 56 + (c - 1)];
            dst[i] = f2bf(v);
        }
        return;
    }
    int idx = (bid - 2048) * 256 + threadIdx.x;   // (o,c) pair
    if (idx >= 128 * 64) return;
    int o = idx >> 6, c = idx & 63;
    const bool v2 = (o >= 64);
    const float Hm[4][4]  = {{1,1,1,1},{1,-1,1,-1},{1,1,-1,-1},{1,-1,-1,1}};
    const float H2m[4][4] = {{1,-1,1,-1},{1,1,1,1},{1,1,-1,-1},{1,-1,-1,1}};

    float wv[4][4];
    #pragma unroll
    for (int i = 0; i < 4; ++i)
        #pragma unroll
        for (int j = 0; j < 4; ++j)
            wv[i][j] = w[((o * 64 + c) * 4 + i) * 4 + j];

    float FA[4][4], FB[4][4], G[2][4];
    #pragma unroll
    for (int a = 0; a < 4; ++a)
        #pragma unroll
        for (int i = 0; i < 4; ++i) {
            FA[a][i] = v2 ? H2m[a][i] : Hm[i][a];
            FB[a][i] = v2 ? H2m[a][i] : Hm[a][i];
        }
    #pragma unroll
    for (int p = 0; p < 2; ++p)
        #pragma unroll
        for (int i = 0; i < 4; ++i)
            G[p][i] = 0.25f * (v2 ? H2m[p + 1][i] : Hm[p + 1][i]);

    unsigned char* bstage = ws + BSTG_OFF;
    #pragma unroll
    for (int P = 0; P < 2; ++P)
    #pragma unroll
    for (int Q = 0; Q < 2; ++Q) {
        int nrow = o * 4 + P * 2 + Q;
        int g = nrow >> 7, nl = nrow & 127;
        #pragma unroll
        for (int b = 0; b < 4; ++b)
        #pragma unroll
        for (int a = 0; a < 4; ++a) {
            float s = 0.f;
            #pragma unroll
            for (int i = 0; i < 4; ++i) {
                float sj = 0.f;
                #pragma unroll
                for (int j = 0; j < 4; ++j)
                    sj += FB[b][j] * G[Q][j] * wv[i][j];
                s += G[P][i] * FA[a][i] * sj;
            }
            int kg  = c * 16 + b * 4 + a;
            int k16 = kg >> 6, kk = kg & 63;
            int byte = (nl * 128 + kk * 2) ^ ((nl & 7) << 4);
            *(unsigned short*)(bstage + ((g * 16 + k16) << 14) + byte) = f2bf(s);
        }
    }
}

// ---------------------------------------------------------------------------
// Main: pipelined im2col-GEMM. M=25088 (196x128), N=512 (4x128), K=1024.
// 512 threads = 8 waves (2m x 4n), per-wave 64x32 output, 16x16x32 bf16 MFMA.
// ---------------------------------------------------------------------------
__global__ __launch_bounds__(512) void conv_gemm(
    const unsigned short* __restrict__ xp,
    const unsigned char* __restrict__ bws,
    const float* __restrict__ bias,
    float* __restrict__ out)
{
    __shared__ __align__(16) unsigned char Abuf[128 * 128];  // 16KB
    __shared__ __align__(16) unsigned char Bbuf[128 * 128];  // 16KB
    __shared__ int s_pbase[128];
    __shared__ int s_obase[128];

    const int tid  = threadIdx.x;
    const int lane = tid & 63;
    const int wv   = tid >> 6;              // 0..7
    const int wm   = wv >> 2, wn = wv & 3;  // 2 x 4 wave grid
    const int bid  = blockIdx.x;
    // XCD-chunked swizzle: 784 = 8*98, same-t0 n-groups land on one XCD
    const int wid = (bid & 7) * 98 + (bid >> 3);
    const int tg  = wid >> 2, ng = wid & 3;
    const int t0  = tg << 7, n0g = ng << 7;

    if (tid < 128) {
        int t = t0 + tid;
        int nimg = t / 784, rem = t - nimg * 784;
        int h = rem / 28, w = rem - h * 28;
        s_pbase[tid] = nimg * (64 * 3364) + (2 * h) * 58 + 2 * w;
        s_obase[tid] = nimg * (128 * 3136) + (2 * h) * 56 + 2 * w;
    }
    __syncthreads();

    // A-gather assignment: one (tile,c) pair per thread, tiles lane-fastest
    const int tl = tid & 127, cc = tid >> 7;
    const int ebase0 = s_pbase[tl] + cc * 3364;
    const unsigned char* bsrc = bws + ((size_t)ng << 18);
    const int aw = (tl * 128 + cc * 32) ^ ((tl & 7) << 4);

    // fragment read offsets (XOR swizzle applied to full within-row offset)
    int abase[4], aswz[4], bbase[2], bswz[2];
    #pragma unroll
    for (int fm = 0; fm < 4; ++fm) {
        int m = wm * 64 + fm * 16 + (lane & 15);
        abase[fm] = m * 128 + ((lane >> 4) << 4);
        aswz[fm]  = (m & 7) << 4;
    }
    #pragma unroll
    for (int fn = 0; fn < 2; ++fn) {
        int n = wn * 32 + fn * 16 + (lane & 15);
        bbase[fn] = n * 128 + ((lane >> 4) << 4);
        bswz[fn]  = (n & 7) << 4;
    }

    f32x4 acc[4][2];
    #pragma unroll
    for (int i = 0; i < 4; ++i)
        #pragma unroll
        for (int j = 0; j < 2; ++j)
            acc[i][j] = (f32x4){0.f, 0.f, 0.f, 0.f};

    unsigned int A0[8], A1[8];
    u32x4 B0[2], B1[2];

    auto GATHER_A = [&](int k, unsigned int* A) {
        const unsigned short* p = xp + (ebase0 + k * 13456);  // k*4*3364
        #pragma unroll
        for (int b = 0; b < 4; ++b) {
            A[b * 2]     = *(const unsigned int*)(p + b * 58);
            A[b * 2 + 1] = *(const unsigned int*)(p + b * 58 + 2);
        }
    };
    auto GATHER_B = [&](int k, u32x4* B) {
        const unsigned char* q = bsrc + (k << 14) + tid * 16;
        B[0] = *(const u32x4*)(q);
        B[1] = *(const u32x4*)(q + 8192);
    };
    auto STAGE = [&](const unsigned int* A, const u32x4* B) {
        u32x4 q0 = {A[0], A[1], A[2], A[3]};
        u32x4 q1 = {A[4], A[5], A[6], A[7]};
        *(u32x4*)(Abuf + aw)        = q0;
        *(u32x4*)(Abuf + (aw ^ 16)) = q1;
        *(u32x4*)(Bbuf + tid * 16)        = B[0];
        *(u32x4*)(Bbuf + 8192 + tid * 16) = B[1];
    };
    auto MFMA = [&]() {
        #pragma unroll
        for (int ks = 0; ks < 2; ++ks) {
            bf16x8 af[4], bg[2];
            #pragma unroll
            for (int fm = 0; fm < 4; ++fm)
                af[fm] = *(const bf16x8*)(Abuf + ((abase[fm] | (ks << 6)) ^ aswz[fm]));
            #pragma unroll
            for (int fn = 0; fn < 2; ++fn)
                bg[fn] = *(const bf16x8*)(Bbuf + ((bbase[fn] | (ks << 6)) ^ bswz[fn]));
            #pragma unroll
            for (int fm = 0; fm < 4; ++fm)
                #pragma unroll
                for (int fn = 0; fn < 2; ++fn)
                    acc[fm][fn] = __builtin_amdgcn_mfma_f32_16x16x32_bf16(
                        af[fm], bg[fn], acc[fm][fn], 0, 0, 0);
        }
    };

    GATHER_A(0, A0);
    GATHER_B(0, B0);

    for (int kk = 0; kk < 8; ++kk) {
        STAGE(A0, B0);
        __syncthreads();
        GATHER_A(2 * kk + 1, A1);      // prefetch: in flight during MFMA
        GATHER_B(2 * kk + 1, B1);
        MFMA();
        __syncthreads();

        STAGE(A1, B1);
        __syncthreads();
        if (kk < 7) {
            GATHER_A(2 * kk + 2, A0);
            GATHER_B(2 * kk + 2, B0);
        }
        MFMA();
        __syncthreads();
    }

    // epilogue: D col = lane&15 (n'), row = (lane>>4)*4+reg (m)
    #pragma unroll
    for (int fn = 0; fn < 2; ++fn) {
        int ngl = n0g + wn * 32 + fn * 16 + (lane & 15);
        int o = ngl >> 2, P = (ngl >> 1) & 1, Q = ngl & 1;
        float bo = bias[o];
        int ooff = o * 3136 + P * 56 + Q;
        #pragma unroll
        for (int fm = 0; fm < 4; ++fm) {
            int mb = wm * 64 + fm * 16 + ((lane >> 4) << 2);
            #pragma unroll
            for (int r = 0; r < 4; ++r)
                out[s_obase[mb + r] + ooff] = acc[fm][fn][r] + bo;
        }
    }
}

extern "C" void kernel_launch(void* const* d_in, const int* in_sizes, int n_in,
                              void* d_out, int out_size, void* d_ws, size_t ws_size,
                              hipStream_t stream)
{
    const float* x = (const float*)d_in[0];
    const float* w = (const float*)d_in[1];
    const float* b = (const float*)d_in[2];
    float* out = (float*)d_out;
    unsigned char* ws = (unsigned char*)d_ws;

    hipLaunchKernelGGL(prep, dim3(2048 + 32), dim3(256), 0, stream, x, w, ws);
    hipLaunchKernelGGL(conv_gemm, dim3(784), dim3(512), 0, stream,
                       (const unsigned short*)ws, ws + BSTG_OFF, b, out);
}

// Round 3
// 88.190 us; speedup vs baseline: 1.4655x; 1.0093x over previous
//
#include <hip/hip_runtime.h>

typedef __attribute__((ext_vector_type(8))) short bf16x8;
typedef __attribute__((ext_vector_type(4))) float f32x4;
typedef __attribute__((ext_vector_type(4))) unsigned int u32x4;

#define XP_ELEMS (2048 * 3364)      // padded x, bf16: 32*64 planes of 58x58
#define XP_BYTES (XP_ELEMS * 2)
#define BSTG_OFF XP_BYTES           // staged B: 4 groups * 16 ksteps * 16KB = 1MB

static __device__ __forceinline__ unsigned short f2bf(float v) {
    unsigned int u = __builtin_bit_cast(unsigned int, v);
    u += 0x7fffu + ((u >> 16) & 1u);
    return (unsigned short)(u >> 16);
}

static __device__ __forceinline__ void gload_lds16(const void* g, void* l) {
    __builtin_amdgcn_global_load_lds(
        (const __attribute__((address_space(1))) void*)g,
        (__attribute__((address_space(3))) void*)l, 16, 0, 0);
}

// ---------------------------------------------------------------------------
// Prep: (a) pad+convert x to bf16 58x58 planes (u32-pair stores, coalesced);
// (b) fold Hadamard transforms into weights in the swizzled LDS-tile layout.
// ---------------------------------------------------------------------------
__global__ __launch_bounds__(256) void prep(const float* __restrict__ x,
                                            const float* __restrict__ w,
                                            unsigned char* __restrict__ ws)
{
    int bid = blockIdx.x;
    if (bid < 2048) {
        // one 56x56 f32 plane -> 58x58 bf16 padded plane, as 1682 u32 pairs
        const float* src = x + (size_t)bid * 3136;
        unsigned int* dst = (unsigned int*)ws + (size_t)bid * 1682;
        for (int s = threadIdx.x; s < 1682; s += 256) {
            int r = s / 29, p = s - r * 29;     // row, pair index
            float v0 = 0.f, v1 = 0.f;
            if (r >= 1 && r <= 56) {
                const float* row = src + (r - 1) * 56;
                if (p >= 1)  v0 = row[2 * p - 1];
                if (p <= 27) v1 = row[2 * p];
            }
            dst[s] = (unsigned int)f2bf(v0) | ((unsigned int)f2bf(v1) << 16);
        }
        return;
    }
    int idx = (bid - 2048) * 256 + threadIdx.x;   // (o,c) pair
    if (idx >= 128 * 64) return;
    int o = idx >> 6, c = idx & 63;
    const bool v2 = (o >= 64);
    const float Hm[4][4]  = {{1,1,1,1},{1,-1,1,-1},{1,1,-1,-1},{1,-1,-1,1}};
    const float H2m[4][4] = {{1,-1,1,-1},{1,1,1,1},{1,1,-1,-1},{1,-1,-1,1}};

    float wv[4][4];
    #pragma unroll
    for (int i = 0; i < 4; ++i)
        #pragma unroll
        for (int j = 0; j < 4; ++j)
            wv[i][j] = w[((o * 64 + c) * 4 + i) * 4 + j];

    float FA[4][4], FB[4][4], G[2][4];
    #pragma unroll
    for (int a = 0; a < 4; ++a)
        #pragma unroll
        for (int i = 0; i < 4; ++i) {
            FA[a][i] = v2 ? H2m[a][i] : Hm[i][a];
            FB[a][i] = v2 ? H2m[a][i] : Hm[a][i];
        }
    #pragma unroll
    for (int p = 0; p < 2; ++p)
        #pragma unroll
        for (int i = 0; i < 4; ++i)
            G[p][i] = 0.25f * (v2 ? H2m[p + 1][i] : Hm[p + 1][i]);

    unsigned char* bstage = ws + BSTG_OFF;
    #pragma unroll
    for (int P = 0; P < 2; ++P)
    #pragma unroll
    for (int Q = 0; Q < 2; ++Q) {
        int nrow = o * 4 + P * 2 + Q;
        int g = nrow >> 7, nl = nrow & 127;
        #pragma unroll
        for (int b = 0; b < 4; ++b)
        #pragma unroll
        for (int a = 0; a < 4; ++a) {
            float s = 0.f;
            #pragma unroll
            for (int i = 0; i < 4; ++i) {
                float sj = 0.f;
                #pragma unroll
                for (int j = 0; j < 4; ++j)
                    sj += FB[b][j] * G[Q][j] * wv[i][j];
                s += G[P][i] * FA[a][i] * sj;
            }
            int kg  = c * 16 + b * 4 + a;
            int k16 = kg >> 6, kk = kg & 63;
            int byte = (nl * 128 + kk * 2) ^ ((nl & 7) << 4);
            *(unsigned short*)(bstage + ((g * 16 + k16) << 14) + byte) = f2bf(s);
        }
    }
}

// ---------------------------------------------------------------------------
// Main: 2-phase double-buffered im2col-GEMM (T3 minimum recipe + T14).
// M=25088 (196x128), N=512 (4x128), K=1024 (16x64). One barrier per K-step.
// 512 threads = 8 waves (2m x 4n), per-wave 64x32 out, 16x16x32 bf16 MFMA.
// ---------------------------------------------------------------------------
__global__ __launch_bounds__(512) void conv_gemm(
    const unsigned short* __restrict__ xp,
    const unsigned char* __restrict__ bws,
    const float* __restrict__ bias,
    float* __restrict__ out)
{
    __shared__ __align__(16) unsigned char Abuf[2][16384];
    __shared__ __align__(16) unsigned char Bbuf[2][16384];
    __shared__ int s_pbase[128];
    __shared__ int s_obase[128];

    const int tid  = threadIdx.x;
    const int lane = tid & 63;
    const int wv   = tid >> 6;              // 0..7
    const int wm   = wv >> 2, wn = wv & 3;  // 2 x 4 wave grid
    const int bid  = blockIdx.x;
    // XCD-chunked swizzle: 784 = 8*98; 4 N-groups of one A-panel share an XCD
    const int wid = (bid & 7) * 98 + (bid >> 3);
    const int tg  = wid >> 2, ng = wid & 3;
    const int t0  = tg << 7, n0g = ng << 7;

    if (tid < 128) {
        int t = t0 + tid;
        int nimg = t / 784, rem = t - nimg * 784;
        int h = rem / 28, w = rem - h * 28;
        s_pbase[tid] = nimg * (64 * 3364) + (2 * h) * 58 + 2 * w;
        s_obase[tid] = nimg * (128 * 3136) + (2 * h) * 56 + 2 * w;
    }
    __syncthreads();

    // A-gather: one (tile,c) pair per thread
    const int tl = tid & 127, cc = tid >> 7;
    const int ebase0 = s_pbase[tl] + cc * 3364;
    const int aw = (tl * 128 + cc * 32) ^ ((tl & 7) << 4);
    const unsigned char* bsrc = bws + ((size_t)ng << 18) + tid * 16;

    // fragment read offsets (XOR-swizzled)
    int abase[4], aswz[4], bbase[2], bswz[2];
    #pragma unroll
    for (int fm = 0; fm < 4; ++fm) {
        int m = wm * 64 + fm * 16 + (lane & 15);
        abase[fm] = m * 128 + ((lane >> 4) << 4);
        aswz[fm]  = (m & 7) << 4;
    }
    #pragma unroll
    for (int fn = 0; fn < 2; ++fn) {
        int n = wn * 32 + fn * 16 + (lane & 15);
        bbase[fn] = n * 128 + ((lane >> 4) << 4);
        bswz[fn]  = (n & 7) << 4;
    }

    f32x4 acc[4][2];
    #pragma unroll
    for (int i = 0; i < 4; ++i)
        #pragma unroll
        for (int j = 0; j < 2; ++j)
            acc[i][j] = (f32x4){0.f, 0.f, 0.f, 0.f};

    unsigned int Areg[8];

    auto GATHER_A = [&](int k) {
        const unsigned short* p = xp + (ebase0 + k * 13456);  // k*4*3364
        #pragma unroll
        for (int b = 0; b < 4; ++b) {
            Areg[b * 2]     = *(const unsigned int*)(p + b * 58);
            Areg[b * 2 + 1] = *(const unsigned int*)(p + b * 58 + 2);
        }
    };
    auto ISSUE_B = [&](int k, int buf) {
        const unsigned char* g = bsrc + (k << 14);
        gload_lds16(g,        &Bbuf[buf][wv * 1024]);
        gload_lds16(g + 8192, &Bbuf[buf][8192 + wv * 1024]);
    };
    auto STAGE_A = [&](int buf) {
        u32x4 q0 = {Areg[0], Areg[1], Areg[2], Areg[3]};
        u32x4 q1 = {Areg[4], Areg[5], Areg[6], Areg[7]};
        *(u32x4*)(Abuf[buf] + aw)        = q0;
        *(u32x4*)(Abuf[buf] + (aw ^ 16)) = q1;
    };
    auto MFMA = [&](int buf) {
        const unsigned char* Ab = Abuf[buf];
        const unsigned char* Bb = Bbuf[buf];
        #pragma unroll
        for (int ks = 0; ks < 2; ++ks) {
            bf16x8 af[4], bg[2];
            #pragma unroll
            for (int fm = 0; fm < 4; ++fm)
                af[fm] = *(const bf16x8*)(Ab + ((abase[fm] | (ks << 6)) ^ aswz[fm]));
            #pragma unroll
            for (int fn = 0; fn < 2; ++fn)
                bg[fn] = *(const bf16x8*)(Bb + ((bbase[fn] | (ks << 6)) ^ bswz[fn]));
            #pragma unroll
            for (int fm = 0; fm < 4; ++fm)
                #pragma unroll
                for (int fn = 0; fn < 2; ++fn)
                    acc[fm][fn] = __builtin_amdgcn_mfma_f32_16x16x32_bf16(
                        af[fm], bg[fn], acc[fm][fn], 0, 0, 0);
        }
    };

    // prologue: fill buffer 0
    GATHER_A(0);
    ISSUE_B(0, 0);
    STAGE_A(0);
    __syncthreads();

    // steady state: one barrier per K-step; loads for k+1 fly under MFMA(k)
    #pragma unroll 2
    for (int k = 0; k < 16; ++k) {
        const int cur = k & 1;
        if (k < 15) {
            GATHER_A(k + 1);            // A into regs (oldest vmem ops)
            ISSUE_B(k + 1, cur ^ 1);    // B direct to alt LDS buffer
        }
        MFMA(cur);                      // covers load latency
        if (k < 15) STAGE_A(cur ^ 1);   // waits A-regs only, then ds_write
        __syncthreads();                // single drain per K-step
    }

    // epilogue: D col = lane&15 (n'), row = (lane>>4)*4+reg (m)
    #pragma unroll
    for (int fn = 0; fn < 2; ++fn) {
        int ngl = n0g + wn * 32 + fn * 16 + (lane & 15);
        int o = ngl >> 2, P = (ngl >> 1) & 1, Q = ngl & 1;
        float bo = bias[o];
        int ooff = o * 3136 + P * 56 + Q;
        #pragma unroll
        for (int fm = 0; fm < 4; ++fm) {
            int mb = wm * 64 + fm * 16 + ((lane >> 4) << 2);
            #pragma unroll
            for (int r = 0; r < 4; ++r)
                out[s_obase[mb + r] + ooff] = acc[fm][fn][r] + bo;
        }
    }
}

extern "C" void kernel_launch(void* const* d_in, const int* in_sizes, int n_in,
                              void* d_out, int out_size, void* d_ws, size_t ws_size,
                              hipStream_t stream)
{
    const float* x = (const float*)d_in[0];
    const float* w = (const float*)d_in[1];
    const float* b = (const float*)d_in[2];
    float* out = (float*)d_out;
    unsigned char* ws = (unsigned char*)d_ws;

    hipLaunchKernelGGL(prep, dim3(2048 + 32), dim3(256), 0, stream, x, w, ws);
    hipLaunchKernelGGL(conv_gemm, dim3(784), dim3(512), 0, stream,
                       (const unsigned short*)ws, ws + BSTG_OFF, b, out);
}